// Round 2
// baseline (419.031 us; speedup 1.0000x reference)
//
#include <hip/hip_runtime.h>

// FFLayer: out = relu( (x / (||x||_2 + 1e-4)) @ W^T + b )
// x: [131072, 1024] f32, W: [256, 1024] f32, b: [256] f32, out: [131072, 256] f32
//
// Round 2: latency-bound fix. B read directly from L2 (Wb = 512 KB, L2-fits;
// no LDS staging, no global_load_lds -> no vmcnt(0) drain at barriers).
// A (x) reg-staged depth-2, LDS only for the A tile, raw s_barrier +
// lgkmcnt(0)-only waits so x loads stay in flight across barriers.

#define IN_F   1024
#define OUT_F  256
#define BATCH  131072
#define BM     64
#define BK     64
#define NKT    (IN_F / BK)   // 16
#define EPSV   1e-4f

typedef __attribute__((ext_vector_type(8))) __bf16 bf16x8;
typedef __attribute__((ext_vector_type(4))) __bf16 bf16x4;
typedef __attribute__((ext_vector_type(4))) float  f32x4;

// W (f32 [256][1024]) -> bf16 [256][1024] in d_ws (512 KB)
__global__ void wconv_kernel(const float* __restrict__ W, __bf16* __restrict__ Wb) {
  const int t = blockIdx.x * blockDim.x + threadIdx.x;
  const float4 v = reinterpret_cast<const float4*>(W)[t];
  bf16x4 h;
  h[0] = (__bf16)v.x; h[1] = (__bf16)v.y; h[2] = (__bf16)v.z; h[3] = (__bf16)v.w;
  reinterpret_cast<bf16x4*>(Wb)[t] = h;
}

__global__ __launch_bounds__(512, 4)
void ffl_kernel(const float* __restrict__ x, const __bf16* __restrict__ Wb,
                const float* __restrict__ bias, float* __restrict__ out) {
  __shared__ __bf16 Ab[2][BM * BK];   // 2 x 8 KB, XOR-swizzled

  const int tid  = threadIdx.x;
  const int lane = tid & 63;
  const int wave = tid >> 6;     // 8 waves, 2(M) x 4(N)
  const int wr   = wave >> 2;
  const int wc   = wave & 3;
  const size_t block_row = (size_t)blockIdx.x * BM;

  // A staging: thread stages row ar, 32-B granule ag (fixed row -> local sumsq)
  const int ar = tid >> 3;
  const int ag = tid & 7;
  const float* xp = x + (block_row + ar) * IN_F + ag * 8;
  const int a_byte = ar * 128 + ((ag * 16) ^ ((ar & 7) << 4));

  const int rm = lane & 15;
  const int q  = lane >> 4;

  // Direct-B fragment base: row (wc*64 + n*16 + rm) of Wb, k-granule q*8
  const __bf16* wp0 = Wb + (size_t)(wc * 64 + rm) * IN_F + q * 8;

  f32x4 acc[2][4];
  #pragma unroll
  for (int m = 0; m < 2; ++m)
    #pragma unroll
    for (int n = 0; n < 4; ++n)
      acc[m][n] = (f32x4){0.f, 0.f, 0.f, 0.f};

  float sumsq = 0.f;

  auto wrA = [&](int buf, const float4& lo, const float4& hi) {
    sumsq += lo.x*lo.x + lo.y*lo.y + lo.z*lo.z + lo.w*lo.w
           + hi.x*hi.x + hi.y*hi.y + hi.z*hi.z + hi.w*hi.w;
    bf16x8 h;
    h[0]=(__bf16)lo.x; h[1]=(__bf16)lo.y; h[2]=(__bf16)lo.z; h[3]=(__bf16)lo.w;
    h[4]=(__bf16)hi.x; h[5]=(__bf16)hi.y; h[6]=(__bf16)hi.z; h[7]=(__bf16)hi.w;
    *reinterpret_cast<bf16x8*>((char*)Ab[buf] + a_byte) = h;
  };

  // Prologue: x[0] -> Ab[0]; x[1] in regs (in flight)
  float4 h0 = *(const float4*)(xp);
  float4 h1 = *(const float4*)(xp + 4);
  float4 n0 = *(const float4*)(xp + BK);
  float4 n1 = *(const float4*)(xp + BK + 4);
  wrA(0, h0, h1);
  asm volatile("s_waitcnt lgkmcnt(0)" ::: "memory");
  __builtin_amdgcn_s_barrier();
  asm volatile("" ::: "memory");

  #pragma unroll
  for (int kt = 0; kt < NKT; ++kt) {
    const int cur = kt & 1;

    // 1) depth-2 x prefetch (clamped, stays in flight across 2 barriers)
    const int ktp = (kt + 2 < NKT) ? (kt + 2) : (NKT - 1);
    const float4 f0 = *(const float4*)(xp + ktp * BK);
    const float4 f1 = *(const float4*)(xp + ktp * BK + 4);

    // 2) stage A[kt+1] (regs loaded one full iteration ago -> latency hidden)
    if (kt + 1 < NKT) wrA(cur ^ 1, n0, n1);

    // 3) compute on Ab[cur] with direct-from-L2 B fragments
    bf16x8 aF[2][2];
    #pragma unroll
    for (int m = 0; m < 2; ++m) {
      const int ra = wr * 32 + m * 16 + rm;
      const char* ab = (const char*)Ab[cur] + ra * 128;
      const int sw = (ra & 7) << 4;
      aF[m][0] = *reinterpret_cast<const bf16x8*>(ab + ((q * 16) ^ sw));
      aF[m][1] = *reinterpret_cast<const bf16x8*>(ab + ((64 + q * 16) ^ sw));
    }
    #pragma unroll
    for (int n = 0; n < 4; ++n) {
      const __bf16* wpn = wp0 + (size_t)n * 16 * IN_F + kt * BK;
      #pragma unroll
      for (int kk = 0; kk < 2; ++kk) {
        const bf16x8 bF = *reinterpret_cast<const bf16x8*>(wpn + kk * 32);
        acc[0][n] = __builtin_amdgcn_mfma_f32_16x16x32_bf16(aF[0][kk], bF, acc[0][n], 0, 0, 0);
        acc[1][n] = __builtin_amdgcn_mfma_f32_16x16x32_bf16(aF[1][kk], bF, acc[1][n], 0, 0, 0);
      }
    }

    // 4) LDS-only barrier (x loads NOT drained)
    asm volatile("s_waitcnt lgkmcnt(0)" ::: "memory");
    __builtin_amdgcn_s_barrier();
    asm volatile("" ::: "memory");

    // 5) rotate
    n0 = f0; n1 = f1;
  }

  // ---- row L2-norm: reduce across the 8 staging threads of each row
  sumsq += __shfl_xor(sumsq, 1);
  sumsq += __shfl_xor(sumsq, 2);
  sumsq += __shfl_xor(sumsq, 4);
  float* norms = reinterpret_cast<float*>(Ab[0]);
  if (ag == 0) norms[ar] = 1.0f / (sqrtf(sumsq) + EPSV);
  __syncthreads();   // post-loop full sync (drains leftover clamped prefetch)

  // ---- epilogue: scale by inv_norm, +bias, relu, store
  const int col0 = wc * 64 + rm;
  #pragma unroll
  for (int n = 0; n < 4; ++n) {
    const float bn = bias[col0 + n * 16];
    #pragma unroll
    for (int m = 0; m < 2; ++m) {
      #pragma unroll
      for (int j = 0; j < 4; ++j) {
        const int lr = wr * 32 + m * 16 + q * 4 + j;
        const float v = fmaxf(acc[m][n][j] * norms[lr] + bn, 0.f);
        out[(block_row + lr) * OUT_F + col0 + n * 16] = v;
      }
    }
  }
}

extern "C" void kernel_launch(void* const* d_in, const int* in_sizes, int n_in,
                              void* d_out, int out_size, void* d_ws, size_t ws_size,
                              hipStream_t stream) {
  const float* x = (const float*)d_in[0];
  const float* W = (const float*)d_in[1];
  const float* b = (const float*)d_in[2];
  float* out = (float*)d_out;
  __bf16* Wb = (__bf16*)d_ws;   // 512 KB scratch

  wconv_kernel<<<(OUT_F * IN_F / 4) / 256, 256, 0, stream>>>(W, Wb);
  ffl_kernel<<<BATCH / BM, 512, 0, stream>>>(x, Wb, b, out);
}